// Round 5
// baseline (226.663 us; speedup 1.0000x reference)
//
#include <hip/hip_runtime.h>
#include <hip/hip_bf16.h>
#include <math.h>

#define B_N   2000
#define T_N   32
#define CIN_N 32
#define COUT_N 128
#define E_N   32000
#define NEG_S 0.01f
#define EPS_S 1e-5f
#define NNODE (B_N * T_N)   // 64000
#define EPAD_N 38016        // padded CSR capacity (multiple-of-4 per node)

typedef __attribute__((ext_vector_type(8))) __bf16 bf16x8;
typedef __attribute__((ext_vector_type(4))) float f32x4;

__device__ __forceinline__ unsigned short f2bf(float f) {
  unsigned u = __builtin_bit_cast(unsigned, f);
  u += 0x7FFFu + ((u >> 16) & 1u);   // RNE (finite values)
  return (unsigned short)(u >> 16);
}
__device__ __forceinline__ float bf2f(unsigned short h) {
  unsigned u = ((unsigned)h) << 16;
  return __builtin_bit_cast(float, u);
}

// ---------------- Kernel 0a: conv weights fp32 -> bf16 (layout [co][96] is already B-operand) ----
__global__ void k_cwcast(const float* __restrict__ cw, unsigned short* __restrict__ wTc)
{
  int idx = blockIdx.x * 256 + threadIdx.x;   // 12288
  if (idx >= 128 * 96) return;
  wTc[idx] = f2bf(cw[idx]);
}

// ---------------- Kernel 0b: tag weights [3][128][128] -> bf16 [col j][concat K] ----------------
__global__ void k_twt(const float* __restrict__ tw, unsigned short* __restrict__ wTt)
{
  int idx = blockIdx.x * 256 + threadIdx.x;   // 49152
  if (idx >= 128 * 384) return;
  int j = idx / 384, kk = idx - j * 384;
  int k = kk >> 7, i = kk & 127;
  wTt[idx] = f2bf(tw[k * 16384 + i * 128 + j]);
}

// ---------------- Kernel 1a: im2col A[t*B+b][k] bf16, k = ci*3+kk, causal pad ----------------
__global__ __launch_bounds__(256) void k_im2col(const float* __restrict__ x,
                                                unsigned short* __restrict__ A)
{
  __shared__ float sx[32 * 34];   // x[b] padded: sx[ci*34 + t+2] = x[b,ci,t]
  const int b = blockIdx.x;
  const int tid = threadIdx.x;
  for (int idx = tid; idx < 1088; idx += 256) {
    int ci = idx / 34, tt = idx - ci * 34;
    sx[idx] = (tt >= 2) ? x[b * 1024 + ci * 32 + (tt - 2)] : 0.f;
  }
  __syncthreads();
  #pragma unroll
  for (int i = 0; i < 12; ++i) {
    int idx = i * 256 + tid;                 // 3072 = 32*96
    int t = idx / 96, k = idx - t * 96;
    int ci = k / 3, kk = k - ci * 3;
    A[(size_t)(t * B_N + b) * 96 + k] = f2bf(sx[ci * 34 + t + kk]);
  }
}

// ---------------- Kernel 1b: MFMA conv GEMM M=64000 K=96 N=128 + bias + LeakyReLU ----------------
// Writes pre-LN bf16 into xcat cols 0..127. No LDS.
__global__ __launch_bounds__(256) void k_convmm(
    const unsigned short* __restrict__ A, const unsigned short* __restrict__ wTc,
    const float* __restrict__ cb, unsigned short* __restrict__ xcat)
{
  const int wid = (blockIdx.x * 256 + threadIdx.x) >> 6;
  const int lane = threadIdx.x & 63;
  const int m0 = wid * 16;
  const int r = lane & 15, q = lane >> 4;

  const bf16x8* arow = (const bf16x8*)(A + (size_t)(m0 + r) * 96 + q * 8);
  const bf16x8* brow = (const bf16x8*)(wTc + (size_t)r * 96 + q * 8);

  f32x4 acc[8] = {};
  #pragma unroll
  for (int ks = 0; ks < 3; ++ks) {
    bf16x8 a = arow[ks * 4];
    #pragma unroll
    for (int nf = 0; nf < 8; ++nf) {
      bf16x8 bv = brow[nf * 192 + ks * 4];   // col block nf*16 -> nf*16*96/8 vecs
      acc[nf] = __builtin_amdgcn_mfma_f32_16x16x32_bf16(a, bv, acc[nf], 0, 0, 0);
    }
  }

  #pragma unroll
  for (int nf = 0; nf < 8; ++nf) {
    const int col = nf * 16 + r;
    const float bias = cb[col];
    #pragma unroll
    for (int i = 0; i < 4; ++i) {
      const int row = m0 + q * 4 + i;
      float u = acc[nf][i] + bias;
      u = (u >= 0.f) ? u : NEG_S * u;
      xcat[(size_t)row * 384 + col] = f2bf(u);
    }
  }
}

// ---------------- Kernel 1c: per-sample LayerNorm in place over xcat cols 0..127 ----------------
__global__ __launch_bounds__(256) void k_ln(
    unsigned short* xcat, const float* __restrict__ gamma, const float* __restrict__ beta)
{
  __shared__ float red1[4], red2[4], sstat[2];
  const int b = blockIdx.x;
  const int tid = threadIdx.x;
  float vals[16];
  float s1 = 0.f, s2 = 0.f;
  #pragma unroll
  for (int i = 0; i < 16; ++i) {
    int idx = i * 256 + tid;
    int t = idx >> 7, c = idx & 127;
    float v = bf2f(xcat[(size_t)(t * B_N + b) * 384 + c]);
    vals[i] = v; s1 += v; s2 += v * v;
  }
  const int lane = tid & 63, wid = tid >> 6;
  #pragma unroll
  for (int d = 32; d > 0; d >>= 1) {
    s1 += __shfl_down(s1, d);
    s2 += __shfl_down(s2, d);
  }
  if (lane == 0) { red1[wid] = s1; red2[wid] = s2; }
  __syncthreads();
  if (tid == 0) {
    float a = red1[0] + red1[1] + red1[2] + red1[3];
    float c = red2[0] + red2[1] + red2[2] + red2[3];
    float mu = a / 4096.f;
    float var = c / 4096.f - mu * mu;
    sstat[0] = mu;
    sstat[1] = rsqrtf(var + EPS_S);
  }
  __syncthreads();
  const float mu = sstat[0], rs = sstat[1];
  #pragma unroll
  for (int i = 0; i < 16; ++i) {
    int idx = i * 256 + tid;
    int t = idx >> 7, c = idx & 127;
    float g  = gamma[c * 32 + t];
    float be = beta[c * 32 + t];
    xcat[(size_t)(t * B_N + b) * 384 + c] = f2bf((vals[i] - mu) * rs * g + be);
  }
}

// ---------------- Kernel 2: in-degree (weighted) + in-edge counts ----------------
__global__ void k_deg(const int* __restrict__ ei, const float* __restrict__ ew,
                      float* __restrict__ deg, int* __restrict__ cnt)
{
  int e = blockIdx.x * 256 + threadIdx.x;
  if (e >= E_N) return;
  int d = ei[E_N + e];
  atomicAdd(&deg[d], ew[e]);
  atomicAdd(&cnt[d], 1);
}

// ---------------- Kernel 3: single-block exclusive scan over 2000 PADDED counts ----------------
__global__ __launch_bounds__(256) void k_scan(const int* __restrict__ cnt, int* __restrict__ offs)
{
  __shared__ int wsum[4];
  int tid = threadIdx.x;
  int vals[8];
  int run = 0;
  #pragma unroll
  for (int i = 0; i < 8; ++i) {
    int idx = tid * 8 + i;
    vals[i] = run;
    int v = (idx < B_N) ? cnt[idx] : 0;
    v = (v + 3) & ~3;                       // pad to multiple of 4
    run += v;
  }
  int lane = tid & 63, wid = tid >> 6;
  int xs = run;
  #pragma unroll
  for (int d = 1; d < 64; d <<= 1) {
    int y = __shfl_up(xs, d);
    if (lane >= d) xs += y;
  }
  if (lane == 63) wsum[wid] = xs;
  __syncthreads();
  int pre = 0;
  for (int w = 0; w < wid; ++w) pre += wsum[w];
  int excl = pre + xs - run;
  #pragma unroll
  for (int i = 0; i < 8; ++i) {
    int idx = tid * 8 + i;
    if (idx <= B_N) offs[idx] = excl + vals[i];
  }
}

// ---------------- Kernel 4: CSR scatter + edge norm (pad slots stay {src=0, norm=0}) ----------------
__global__ void k_scatter(const int* __restrict__ ei, const float* __restrict__ ew,
                          const float* __restrict__ deg, const int* __restrict__ offs,
                          int* __restrict__ cursor, int* __restrict__ csr_src,
                          float* __restrict__ csr_norm)
{
  int e = blockIdx.x * 256 + threadIdx.x;
  if (e >= E_N) return;
  int s = ei[e], d = ei[E_N + e];
  float ds_ = deg[s], dd = deg[d];
  float dis_s = (ds_ > 0.f) ? rsqrtf(fmaxf(ds_, 1e-12f)) : 0.f;
  float dis_d = (dd  > 0.f) ? rsqrtf(fmaxf(dd,  1e-12f)) : 0.f;
  float nrm = dis_s * ew[e] * dis_d;
  int pos = offs[d] + atomicAdd(&cursor[d], 1);
  csr_src[pos] = s;
  csr_norm[pos] = nrm;
}

// ---------------- Kernel 5: one-hop propagation, 4-wide edge unroll ----------------
__global__ __launch_bounds__(256) void k_prop(
    unsigned short* xcat, int cin, int cout_,
    const int* __restrict__ offs, const int* __restrict__ csr_src,
    const float* __restrict__ csr_norm)
{
  int gw = (blockIdx.x * 256 + threadIdx.x) >> 6;
  int lane = threadIdx.x & 63;
  if (gw >= NNODE) return;
  int t = gw / B_N;
  int b = gw - t * B_N;
  int beg = offs[b], end = offs[b + 1];           // both multiples of 4
  const unsigned short* base = xcat + (size_t)t * B_N * 384 + cin + lane * 2;
  float ax0 = 0.f, ay0 = 0.f, ax1 = 0.f, ay1 = 0.f;
  float ax2 = 0.f, ay2 = 0.f, ax3 = 0.f, ay3 = 0.f;
  for (int i = beg; i < end; i += 4) {
    int4   s4 = *(const int4*)&csr_src[i];
    float4 n4 = *(const float4*)&csr_norm[i];
    ushort2 v0 = *(const ushort2*)(base + (size_t)s4.x * 384);
    ushort2 v1 = *(const ushort2*)(base + (size_t)s4.y * 384);
    ushort2 v2 = *(const ushort2*)(base + (size_t)s4.z * 384);
    ushort2 v3 = *(const ushort2*)(base + (size_t)s4.w * 384);
    ax0 += n4.x * bf2f(v0.x); ay0 += n4.x * bf2f(v0.y);
    ax1 += n4.y * bf2f(v1.x); ay1 += n4.y * bf2f(v1.y);
    ax2 += n4.z * bf2f(v2.x); ay2 += n4.z * bf2f(v2.y);
    ax3 += n4.w * bf2f(v3.x); ay3 += n4.w * bf2f(v3.y);
  }
  float ax = (ax0 + ax1) + (ax2 + ax3);
  float ay = (ay0 + ay1) + (ay2 + ay3);
  ushort2 o; o.x = f2bf(ax); o.y = f2bf(ay);
  *(ushort2*)&xcat[(size_t)gw * 384 + cout_ + lane * 2] = o;
}

// ---------------- Kernel 6: MFMA triple-GEMM (K=384) + bias + LeakyReLU + residual ----------------
__global__ __launch_bounds__(256) void k_gemm(
    const unsigned short* __restrict__ xcat, const unsigned short* __restrict__ wTt,
    const float* __restrict__ tb, float* __restrict__ outn)
{
  const int wid = (blockIdx.x * 256 + threadIdx.x) >> 6;
  const int lane = threadIdx.x & 63;
  const int m0 = wid * 16;
  const int r = lane & 15, q = lane >> 4;

  const bf16x8* arow = (const bf16x8*)(xcat + (size_t)(m0 + r) * 384 + q * 8);
  const bf16x8* brow = (const bf16x8*)(wTt + (size_t)r * 384 + q * 8);

  f32x4 acc[8] = {};
  #pragma unroll
  for (int ks = 0; ks < 12; ++ks) {
    bf16x8 a = arow[ks * 4];
    #pragma unroll
    for (int nf = 0; nf < 8; ++nf) {
      bf16x8 bf = brow[nf * 768 + ks * 4];
      acc[nf] = __builtin_amdgcn_mfma_f32_16x16x32_bf16(a, bf, acc[nf], 0, 0, 0);
    }
  }

  #pragma unroll
  for (int nf = 0; nf < 8; ++nf) {
    const int col = nf * 16 + r;
    const float bias = tb[col];
    #pragma unroll
    for (int i = 0; i < 4; ++i) {
      const int row = m0 + q * 4 + i;
      float u = acc[nf][i] + bias;
      u = (u >= 0.f) ? u : NEG_S * u;
      float xv = bf2f(xcat[(size_t)row * 384 + col]);
      outn[(size_t)row * 128 + col] = xv + u;
    }
  }
}

// ---------------- Kernel 7: transpose [t*B+b][c] -> [b][c][t] ----------------
__global__ __launch_bounds__(256) void k_out(const float* __restrict__ hfin, float* __restrict__ out)
{
  __shared__ float lds[32 * 129];
  const int b = blockIdx.x, tid = threadIdx.x;
  #pragma unroll
  for (int i = 0; i < 16; ++i) {
    int idx = i * 256 + tid;
    int t = idx >> 7, c = idx & 127;
    lds[t * 129 + c] = hfin[(size_t)(t * B_N + b) * 128 + c];
  }
  __syncthreads();
  #pragma unroll
  for (int i = 0; i < 16; ++i) {
    int idx = i * 256 + tid;
    int c = idx >> 5, t = idx & 31;
    out[(size_t)b * 4096 + c * 32 + t] = lds[t * 129 + c];
  }
}

extern "C" void kernel_launch(void* const* d_in, const int* in_sizes, int n_in,
                              void* d_out, int out_size, void* d_ws, size_t ws_size,
                              hipStream_t stream)
{
  const float* x     = (const float*)d_in[0];
  const int*   ei    = (const int*)d_in[1];
  const float* ew    = (const float*)d_in[2];
  const float* cw    = (const float*)d_in[3];
  const float* cb    = (const float*)d_in[4];
  const float* gamma = (const float*)d_in[5];
  const float* beta  = (const float*)d_in[6];
  const float* tw    = (const float*)d_in[7];
  const float* tb    = (const float*)d_in[8];
  float* out = (float*)d_out;

  // workspace layout
  float* outn = (float*)d_ws;                                             // 64000*128 fp32
  unsigned short* A = (unsigned short*)outn;                              // 64000*96 bf16, aliased:
                                                                          // dead before k_gemm writes outn
  unsigned short* xcat = (unsigned short*)(outn + (size_t)NNODE * 128);   // 64000*384 bf16
  float* deg = (float*)(xcat + (size_t)NNODE * 384);                      // 2000
  int*   cnt    = (int*)(deg + B_N);                                      // 2000
  int*   cursor = cnt + B_N;                                              // 2000
  int*   offs   = cursor + B_N;                                           // 2001
  int*   csr_src = offs + (B_N + 1);                                      // EPAD_N
  float* csr_norm = (float*)(csr_src + EPAD_N);                           // EPAD_N
  unsigned short* wTc = (unsigned short*)(csr_norm + EPAD_N);             // 128*96 bf16
  unsigned short* wTt = wTc + 128 * 96;                                   // 128*384 bf16

  hipMemsetAsync(deg, 0, (size_t)3 * B_N * 4, stream);                    // deg+cnt+cursor
  hipMemsetAsync(csr_src, 0, (size_t)EPAD_N * 8, stream);                 // csr_src+csr_norm

  k_cwcast<<<(128 * 96 + 255) / 256, 256, 0, stream>>>(cw, wTc);
  k_twt<<<(128 * 384 + 255) / 256, 256, 0, stream>>>(tw, wTt);
  k_im2col<<<B_N, 256, 0, stream>>>(x, A);
  k_convmm<<<NNODE / 16 / 4, 256, 0, stream>>>(A, wTc, cb, xcat);
  k_ln<<<B_N, 256, 0, stream>>>(xcat, gamma, beta);
  k_deg<<<(E_N + 255) / 256, 256, 0, stream>>>(ei, ew, deg, cnt);
  k_scan<<<1, 256, 0, stream>>>(cnt, offs);
  k_scatter<<<(E_N + 255) / 256, 256, 0, stream>>>(ei, ew, deg, offs, cursor, csr_src, csr_norm);
  k_prop<<<NNODE / 4, 256, 0, stream>>>(xcat, 0, 128, offs, csr_src, csr_norm);
  k_prop<<<NNODE / 4, 256, 0, stream>>>(xcat, 128, 256, offs, csr_src, csr_norm);
  k_gemm<<<NNODE / 16 / 4, 256, 0, stream>>>(xcat, wTt, tb, outn);
  k_out<<<B_N, 256, 0, stream>>>(outn, out);
}